// Round 2
// baseline (6284.347 us; speedup 1.0000x reference)
//
#include <hip/hip_runtime.h>
#include <hip/hip_bf16.h>

using bf16 = __hip_bfloat16;

// Problem dims
#define BB 2
#define TT 2048
#define DD 256
#define HH_ 4
#define KK 1024
#define NN 4096
#define VV 32000
#define BT 4096   // BB*TT
#define LL 6

__device__ __forceinline__ float toF(float x) { return x; }
__device__ __forceinline__ float toF(bf16 x) { return __bfloat162float(x); }
__device__ __forceinline__ void storeC(float* p, float v) { *p = v; }
__device__ __forceinline__ void storeC(bf16* p, float v) { *p = __float2bfloat16(v); }

// ---------------- block-wide sum over 256 threads (4 waves) ----------------
__device__ __forceinline__ float block_sum_256(float val, float* sbuf) {
#pragma unroll
    for (int off = 32; off > 0; off >>= 1)
        val += __shfl_down(val, off, 64);
    const int lane = threadIdx.x & 63;
    const int wid  = threadIdx.x >> 6;
    __syncthreads();                 // protect sbuf from any previous use
    if (lane == 0) sbuf[wid] = val;
    __syncthreads();
    return sbuf[0] + sbuf[1] + sbuf[2] + sbuf[3];
}

// ---------------- rope tables (fp64 for angle accuracy) ----------------
__global__ void k_sincos(float* __restrict__ cosT, float* __restrict__ sinT) {
    const int t = blockIdx.x;
    for (int k = threadIdx.x; k < KK; k += blockDim.x) {
        const int f = k & 511;  // k % (KK/2)
        const double invf = exp(-((double)(2 * f) / (double)KK) * 9.210340371976184); // ln(10000)
        const double th = (double)t * invf;
        double s, c;
        sincos(th, &s, &c);
        cosT[t * KK + k] = (float)c;
        sinT[t * KK + k] = (float)s;
    }
}

// ---------------- v = ln(emb[input_]) ----------------
__global__ void k_embed_ln(const int* __restrict__ idx, const float* __restrict__ emb,
                           float* __restrict__ v) {
    __shared__ float sbuf[4];
    const int r = blockIdx.x;                 // [0, BT)
    const int token = idx[r];
    const float xv = emb[(long)token * DD + threadIdx.x];
    const float mu = block_sum_256(xv, sbuf) * (1.f / DD);
    const float d = xv - mu;
    const float var = block_sum_256(d * d, sbuf) * (1.f / DD);
    v[r * DD + threadIdx.x] = d / sqrtf(var + 1e-5f);
}

// ---------------- in-place row LN over D=256 ----------------
__global__ void k_ln_rows(float* __restrict__ a) {
    __shared__ float sbuf[4];
    const int r = blockIdx.x;
    const float xv = a[(long)r * DD + threadIdx.x];
    const float mu = block_sum_256(xv, sbuf) * (1.f / DD);
    const float d = xv - mu;
    const float var = block_sum_256(d * d, sbuf) * (1.f / DD);
    a[(long)r * DD + threadIdx.x] = d / sqrtf(var + 1e-5f);
}

// ---------------- v = ln(v + ln(z)) ----------------
__global__ void k_fin_ln(float* __restrict__ v, const float* __restrict__ z) {
    __shared__ float sbuf[4];
    const int r = blockIdx.x;
    const float zv = z[r * DD + threadIdx.x];
    const float mu1 = block_sum_256(zv, sbuf) * (1.f / DD);
    const float d1 = zv - mu1;
    const float var1 = block_sum_256(d1 * d1, sbuf) * (1.f / DD);
    const float lnz = d1 / sqrtf(var1 + 1e-5f);
    const float u = v[r * DD + threadIdx.x] + lnz;
    const float mu2 = block_sum_256(u, sbuf) * (1.f / DD);
    const float d2 = u - mu2;
    const float var2 = block_sum_256(d2 * d2, sbuf) * (1.f / DD);
    v[r * DD + threadIdx.x] = d2 / sqrtf(var2 + 1e-5f);
}

// ---------------- v += pos ----------------
__global__ void k_addpos(float* __restrict__ v, const float* __restrict__ pos) {
    const int i = blockIdx.x * 256 + threadIdx.x;  // BT*DD total
    const int d = i & (DD - 1);
    const int r = i >> 8;
    const int t = r & (TT - 1);
    v[i] += pos[t * DD + d];
}

// ---------------- q = x*cos + rotate_half(x)*sin ----------------
__global__ void k_rope(const float* __restrict__ x, const float* __restrict__ cosT,
                       const float* __restrict__ sinT, float* __restrict__ q) {
    const int total = BB * HH_ * TT * KK;
    for (int i = blockIdx.x * blockDim.x + threadIdx.x; i < total;
         i += gridDim.x * blockDim.x) {
        const int k = i & (KK - 1);
        const int t = (i >> 10) & (TT - 1);
        const float xv = x[i];
        const float other = (k < KK / 2) ? -x[i + KK / 2] : x[i - KK / 2];
        const int ck = t * KK + k;
        q[i] = xv * cosT[ck] + other * sinT[ck];
    }
}

// ---------------- generic tiled GEMM ----------------
// C[m,n] = epi( sum_k A[m,k] * B[k,n] )          (TA=false)
// C[m,n] = epi( sum_k A[k,m] * B[k,n] )          (TA=true)
// batched over blockIdx.z with offset = (z/HH)*s?o + (z%HH)*s?i for A,B,C,G.
// EPI: 0=none, 1=relu, 2=relu*G
template <bool TA, typename TB, typename TC, int EPI>
__global__ __launch_bounds__(256)
void gemm_k(const float* __restrict__ Ab, const TB* __restrict__ Bb,
            TC* __restrict__ Cb, const float* __restrict__ Gb,
            int M, int N, int Kin, int lda, int ldb, int ldc, int ldg,
            long sAo, long sAi, long sBo, long sBi,
            long sCo, long sCi, long sGo, long sGi, int HH)
{
    const int z = blockIdx.z;
    const int zo = z / HH, zi = z % HH;
    const float* A = Ab + zo * sAo + zi * sAi;
    const TB* B = Bb + zo * sBo + zi * sBi;
    TC* C = Cb + zo * sCo + zi * sCi;
    const float* G = (EPI == 2) ? (Gb + zo * sGo + zi * sGi) : nullptr;

    const int m0 = blockIdx.y * 64;
    const int n0 = blockIdx.x * 64;
    const int tid = threadIdx.x;
    const int tx = tid & 15, ty = tid >> 4;

    __shared__ __align__(16) float As[16][68];
    __shared__ __align__(16) float Bs[16][68];

    float acc[4][4] = {};

    for (int k0 = 0; k0 < Kin; k0 += 16) {
        if (TA) {
            const int mm = tid & 63, kb = tid >> 6;
#pragma unroll
            for (int u = 0; u < 4; ++u) {
                const int kk = kb * 4 + u;
                As[kk][mm] = A[(long)(k0 + kk) * lda + (m0 + mm)];
            }
        } else {
            const int kk = tid & 15, mb = tid >> 4;
#pragma unroll
            for (int u = 0; u < 4; ++u) {
                const int mm = mb + u * 16;
                As[kk][mm] = A[(long)(m0 + mm) * lda + (k0 + kk)];
            }
        }
        {
            const int nn = tid & 63, kb = tid >> 6;
#pragma unroll
            for (int u = 0; u < 4; ++u) {
                const int kk = kb * 4 + u;
                Bs[kk][nn] = toF(B[(long)(k0 + kk) * ldb + (n0 + nn)]);
            }
        }
        __syncthreads();
#pragma unroll
        for (int kk = 0; kk < 16; ++kk) {
            const float4 av = *(const float4*)(&As[kk][ty * 4]);
            const float4 bv = *(const float4*)(&Bs[kk][tx * 4]);
            const float ar[4] = {av.x, av.y, av.z, av.w};
            const float br[4] = {bv.x, bv.y, bv.z, bv.w};
#pragma unroll
            for (int i = 0; i < 4; ++i)
#pragma unroll
                for (int j = 0; j < 4; ++j)
                    acc[i][j] = fmaf(ar[i], br[j], acc[i][j]);
        }
        __syncthreads();
    }

#pragma unroll
    for (int i = 0; i < 4; ++i) {
        const int m = m0 + ty * 4 + i;
#pragma unroll
        for (int j = 0; j < 4; ++j) {
            const int n = n0 + tx * 4 + j;
            float val = acc[i][j];
            if (EPI >= 1) val = fmaxf(val, 0.f);
            if (EPI == 2) val *= G[(long)m * ldg + n];
            storeC(&C[(long)m * ldc + n], val);
        }
    }
}

extern "C" void kernel_launch(void* const* d_in, const int* in_sizes, int n_in,
                              void* d_out, int out_size, void* d_ws, size_t ws_size,
                              hipStream_t stream)
{
    const int* input_ = (const int*)d_in[0];
    const float* emb = (const float*)d_in[1];
    const float* pos = (const float*)d_in[2];
    const float* Dx = (const float*)d_in[3];
    const float* Dy = (const float*)d_in[4];
    const float* E = (const float*)d_in[5];
    const float* readout = (const float*)d_in[6];
    float* out = (float*)d_out;

    // workspace layout (floats); y aliases q (q dead before y-gemm)
    float* ws = (float*)d_ws;
    float* v    = ws + 0;          //  BT*DD           = 1,048,576
    float* cosT = ws + 1048576;    //  TT*KK           = 2,097,152
    float* sinT = ws + 3145728;    //  TT*KK           = 2,097,152
    float* x    = ws + 5242880;    //  BB*HH_*TT*KK    = 16,777,216
    float* q    = ws + 22020096;   //  BB*HH_*TT*KK    = 16,777,216
    float* y    = q;               //  BT*NN           = 16,777,216 (alias)
    float* w    = ws + 38797312;   //  BB*HH_*KK*DD    = 2,097,152
    float* a    = ws + 40894464;   //  BB*HH_*TT*DD    = 4,194,304
    float* zb   = ws + 45088768;   //  BT*DD           = 1,048,576
    // total = 46,137,344 floats = 176 MiB

    k_sincos<<<TT, 256, 0, stream>>>(cosT, sinT);
    k_embed_ln<<<BT, 256, 0, stream>>>(input_, emb, v);

    for (int l = 0; l < LL; ++l) {
        // v += pos
        k_addpos<<<BT, 256, 0, stream>>>(v, pos);

        // x[z] = relu(v[b] @ Dx[h]);  z=b*4+h;  M=2048, N=1024, K=256
        gemm_k<false, float, float, 1><<<dim3(16, 32, 8), 256, 0, stream>>>(
            v, Dx, x, nullptr,
            TT, KK, DD, DD, KK, KK, 0,
            (long)TT * DD, 0,
            0, (long)DD * KK,
            (long)HH_ * TT * KK, (long)TT * KK,
            0, 0, HH_);

        // q = rope(x)
        k_rope<<<8192, 256, 0, stream>>>(x, cosT, sinT, q);

        // w[z] = q[z]^T @ v[b];  M=1024 (k), N=256 (d), K=2048 (t)
        gemm_k<true, float, float, 0><<<dim3(4, 16, 8), 256, 0, stream>>>(
            q, v, w, nullptr,
            KK, DD, TT, KK, DD, DD, 0,
            (long)HH_ * TT * KK, (long)TT * KK,
            (long)TT * DD, 0,
            (long)HH_ * KK * DD, (long)KK * DD,
            0, 0, HH_);

        // a[z] = q[z] @ w[z];  M=2048, N=256, K=1024
        gemm_k<false, float, float, 0><<<dim3(4, 32, 8), 256, 0, stream>>>(
            q, w, a, nullptr,
            TT, DD, KK, KK, DD, DD, 0,
            (long)HH_ * TT * KK, (long)TT * KK,
            (long)HH_ * KK * DD, (long)KK * DD,
            (long)HH_ * TT * DD, (long)TT * DD,
            0, 0, HH_);

        // a = ln(a) rows (B*H*T rows of D)
        k_ln_rows<<<BB * HH_ * TT, 256, 0, stream>>>(a);

        // y[b, t, h*KK + k] = relu(ln_a[z] @ Dy[h]) * x[z];  M=2048, N=1024, K=256
        // NOTE: y aliases q; q is not read after the a-gemm above.
        gemm_k<false, float, float, 2><<<dim3(16, 32, 8), 256, 0, stream>>>(
            a, Dy, y, x,
            TT, KK, DD, DD, KK, NN, KK,
            (long)HH_ * TT * DD, (long)TT * DD,
            0, (long)DD * KK,
            (long)TT * NN, (long)KK,
            (long)HH_ * TT * KK, (long)TT * KK,
            HH_);

        // zb = y @ E;  M=4096, N=256, K=4096
        gemm_k<false, float, float, 0><<<dim3(4, 64, 1), 256, 0, stream>>>(
            y, E, zb, nullptr,
            BT, DD, NN, NN, DD, DD, 0,
            0, 0, 0, 0, 0, 0, 0, 0, HH_);

        // v = ln(v + ln(zb))
        k_fin_ln<<<BT, 256, 0, stream>>>(v, zb);
    }

    // out = v @ readout;  M=4096, N=32000, K=256  (fp32 store)
    gemm_k<false, float, float, 0><<<dim3(VV / 64, BT / 64, 1), 256, 0, stream>>>(
        v, readout, out, nullptr,
        BT, VV, DD, DD, VV, VV, 0,
        0, 0, 0, 0, 0, 0, 0, 0, HH_);
}